// Round 14
// baseline (121.245 us; speedup 1.0000x reference)
//
#include <hip/hip_runtime.h>

#define TT 12
#define NN 128
#define BB 4
#define PP 14

typedef __attribute__((ext_vector_type(8))) short short8;
typedef __attribute__((ext_vector_type(4))) float f32x4;
typedef __attribute__((ext_vector_type(2))) float float2v;
typedef __attribute__((ext_vector_type(2))) unsigned uint2v;

__device__ inline unsigned short f2bf(float x){
  unsigned u = __builtin_bit_cast(unsigned, x);
  u += 0x7fffu + ((u >> 16) & 1u);
  return (unsigned short)(u >> 16);
}
__device__ inline float bf2f(unsigned short h){
  unsigned u = ((unsigned)h) << 16;
  return __builtin_bit_cast(float, u);
}
__device__ inline float fexp2(float x){ return __builtin_amdgcn_exp2f(x); }
__device__ inline float frcp(float x){ return __builtin_amdgcn_rcpf(x); }
__device__ inline float sigf(float x){ return frcp(1.0f + fexp2(x * -1.44269504f)); }

__device__ inline float2v exp2v(float2v x){
  float2v r; r[0]=__builtin_amdgcn_exp2f(x[0]); r[1]=__builtin_amdgcn_exp2f(x[1]); return r;
}
// merged reciprocal: one trans op for both lanes (operands >=1, bounded)
__device__ inline float2v rcpv1(float2v x){
  float r = frcp(x[0]*x[1]);
  float2v o; o[0] = x[1]*r; o[1] = x[0]*r; return o;
}

// r14 restructure: BARRIER-FREE main loop. 1040 blocks x 256 threads.
// Each wave owns 16 sequences end-to-end: computes all 4 hu-slices (48
// MFMA/step) and keeps h in a PER-WAVE 2KB LDS scratch. Within one wave DS
// ops execute in order (reads of h(t) precede writes of h(t+1) in program
// order), so no __syncthreads is needed after the staging barrier — waves
// slide freely, removing the 12-step barrier lockstep that r10-r13 showed
// to be invariant (~88us, busy 52%) under every other structural change.
// group [0,1024): edge (b=g>>8, i=(g&255)>>1, s0=(g&1)*64);
// [1024,1032)=beta, [1032,1040)=gamma.
__global__ __launch_bounds__(256) void lstm_all(
    const float* __restrict__ x_s,
    const float* __restrict__ bWih, const float* __restrict__ bWhh, const float* __restrict__ bb_,
    const float* __restrict__ bfW,  const float* __restrict__ bfb,
    const float* __restrict__ gWih, const float* __restrict__ gWhh, const float* __restrict__ gb_,
    const float* __restrict__ gfW,  const float* __restrict__ gfb,
    const float* __restrict__ cWih, const float* __restrict__ cWhh, const float* __restrict__ cb_,
    const float* __restrict__ cfW,  const float* __restrict__ cfb,
    float* __restrict__ out_epi)
{
  // 48 tiles (4 slices x 4 gates x 3 k-frags) x 64 lanes x 16B = 48KB
  __shared__ __align__(16) unsigned short wfrag[48*64*8];
  __shared__ __align__(16) char hscratch[4*2048];         // per-wave h[16 seq][64 hu] bf16, rotate-swizzled
  __shared__ __align__(16) unsigned short xext[TT*64*8];  // [t][seq 0..63][8] bf16
  __shared__ unsigned short fw_lds[PP*64];                // bf16 projection weights
  __shared__ float fb_lds[PP];

  const int tid = threadIdx.x;
  const int l = tid & 63;
  const int wv = tid >> 6;            // wave 0..3, owns seqs [wv*16, wv*16+16)
  const int col = l & 15, q = l >> 4;

  const int rot = (col & 7) << 4;
  char* hs = hscratch + wv*2048;
  const int r0off = col*128 + (((q<<4) + rot) & 127);
  const int r1off = col*128 + ((64 + (q<<4) + rot) & 127);

  int g = blockIdx.x;
  int mode; const float *Wih, *Whh, *bias, *fW, *fb;
  if (g < 1024)      { mode=0; Wih=cWih; Whh=cWhh; bias=cb_; fW=cfW; fb=cfb; }
  else if (g < 1032) { mode=1; g-=1024; Wih=bWih; Whh=bWhh; bias=bb_; fW=bfW; fb=bfb; }
  else               { mode=2; g-=1032; Wih=gWih; Whh=gWhh; bias=gb_; fW=gfW; fb=gfb; }

  int b, i=0, s0;   // block covers seqs s0..s0+63
  if (mode==0) { b = g >> 8; int rem = g & 255; i = rem >> 1; s0 = (rem & 1) << 6; }
  else         { b = g >> 1; s0 = (g & 1) << 6; }

  // ---- stage per-seq input extension [x | 1 | 0-pad] (bf16), all timesteps
  for (int task = tid; task < TT*64; task += 256) {
    int t = task >> 6, m = task & 63;
    unsigned short* dst = &xext[(t*64+m)*8];
    float v0=0,v1=0,v2=0,v3=0,v4=0,v5=0,v6=0,v7=0;
    if (mode==0) {
      const float* xi = x_s + ((b*TT + t)*NN + i)*3;
      const float* xj = x_s + ((b*TT + t)*NN + (s0+m))*3;
      v0=xi[0]; v1=xi[1]; v2=xi[2]; v3=xj[0]; v4=xj[1]; v5=xj[2]; v6=1.f;
    } else {
      const float* xn = x_s + ((b*TT + t)*NN + (s0+m))*3;
      v0=xn[0]; v1=xn[1]; v2=xn[2]; v3=1.f;
    }
    dst[0]=f2bf(v0); dst[1]=f2bf(v1); dst[2]=f2bf(v2); dst[3]=f2bf(v3);
    dst[4]=f2bf(v4); dst[5]=f2bf(v5); dst[6]=f2bf(v6); dst[7]=f2bf(v7);
  }
  for (int idx = tid; idx < PP*64; idx += 256) fw_lds[idx] = f2bf(fW[idx]);
  if (tid < PP) fb_lds[tid] = fb[tid];
  // zero own wave's h scratch (h(0) = 0) — wave-local, no barrier needed
  for (int idx = l; idx < 512; idx += 64) ((unsigned*)hs)[idx] = 0;

  // ---- stage pre-scaled weight fragments into LDS (fragment-linear)
  // tile = slice*12 + gt*3 + kt; lane slot holds 8 bf16 (16B).
  for (int slot = tid; slot < 48*64; slot += 256) {
    int tile = slot >> 6, lane = slot & 63;
    int w_hs = tile / 12, rem = tile % 12, gt = rem / 3, kt = rem % 3;
    float sc = (gt==2) ? 2.88539008f : -1.44269504f;
    int gate = gt*64 + w_hs*16 + (lane & 15);
    int qq = lane >> 4;
    short8 fr = {0,0,0,0,0,0,0,0};
    if (kt < 2) {
      const float* src = Whh + gate*64 + kt*32 + qq*8;
      #pragma unroll
      for (int jj = 0; jj < 8; ++jj) fr[jj] = (short)f2bf(src[jj]*sc);
    } else if (qq == 0) {
      if (mode==0) {
        fr[0]=(short)f2bf(Wih[gate*6+0]*sc); fr[1]=(short)f2bf(Wih[gate*6+1]*sc); fr[2]=(short)f2bf(Wih[gate*6+2]*sc);
        fr[3]=(short)f2bf(Wih[gate*6+3]*sc); fr[4]=(short)f2bf(Wih[gate*6+4]*sc); fr[5]=(short)f2bf(Wih[gate*6+5]*sc);
        fr[6]=(short)f2bf(bias[gate]*sc);
      } else {
        fr[0]=(short)f2bf(Wih[gate*3+0]*sc); fr[1]=(short)f2bf(Wih[gate*3+1]*sc); fr[2]=(short)f2bf(Wih[gate*3+2]*sc);
        fr[3]=(short)f2bf(bias[gate]*sc);
      }
    }
    *(short8*)&wfrag[slot*8] = fr;
  }

  __syncthreads();   // the ONLY barrier: weights/xext/fw staged

  // persistent c-state: [slice][half] float2v
  float2v c0s[4], c1s[4];
  #pragma unroll
  for (int s = 0; s < 4; ++s) { c0s[s] = (float2v){0.f,0.f}; c1s[s] = (float2v){0.f,0.f}; }

#define MM(acc, aop, bop) acc = __builtin_amdgcn_mfma_f32_16x16x32_bf16(aop, bop, acc, 0,0,0)
#define CELL(cvar, hvar, fF, fI, fG, fO) { \
    float2v Ei = exp2v(fI), Ef = exp2v(fF), Eg = exp2v(fG), Eo = exp2v(fO); \
    float2v t1 = (Ei + 1.0f) * (Eg + 1.0f); \
    float2v pf = Ef + 1.0f; \
    float2v num = cvar * t1 + pf * (Eg - 1.0f); \
    cvar = num * rcpv1(pf * t1); \
    float2v Ec = exp2v(cvar * 2.88539008f); \
    hvar = (Ec - 1.0f) * rcpv1((Ec + 1.0f) * (Eo + 1.0f)); }

  for (int t = 0; t < TT; ++t) {
    // reads of h(t) issue before writes of h(t+1): per-wave DS ordering
    short8 b0 = *(const short8*)(hs + r0off);
    short8 b1 = *(const short8*)(hs + r1off);
    short8 bx = *(const short8*)&xext[(t*64 + wv*16 + col)*8];
    #pragma unroll
    for (int s = 0; s < 4; ++s) {
      const unsigned short* wb = &wfrag[((s*12)*64 + l)*8];
      f32x4 Fv = {0.f,0.f,0.f,0.f}, Iv = Fv, Gv = Fv, Ov = Fv;
      // gt order f,i,g,o (gt index 1,0,2,3); frag stride 64*8 shorts = 512
      MM(Fv, *(const short8*)(wb + 3*512), b0);
      MM(Iv, *(const short8*)(wb + 0*512), b0);
      MM(Gv, *(const short8*)(wb + 6*512), b0);
      MM(Ov, *(const short8*)(wb + 9*512), b0);
      MM(Fv, *(const short8*)(wb + 4*512), b1);
      MM(Iv, *(const short8*)(wb + 1*512), b1);
      MM(Gv, *(const short8*)(wb + 7*512), b1);
      MM(Ov, *(const short8*)(wb + 10*512), b1);
      MM(Fv, *(const short8*)(wb + 5*512), bx);
      MM(Iv, *(const short8*)(wb + 2*512), bx);
      MM(Gv, *(const short8*)(wb + 8*512), bx);
      MM(Ov, *(const short8*)(wb + 11*512), bx);
      float2v f0 = {Fv[0],Fv[1]}, f1 = {Fv[2],Fv[3]};
      float2v i0 = {Iv[0],Iv[1]}, i1 = {Iv[2],Iv[3]};
      float2v g0v = {Gv[0],Gv[1]}, g1v = {Gv[2],Gv[3]};
      float2v o0 = {Ov[0],Ov[1]}, o1 = {Ov[2],Ov[3]};
      float2v h0, h1;
      CELL(c0s[s], h0, f0, i0, g0v, o0);
      CELL(c1s[s], h1, f1, i1, g1v, o1);
      unsigned plo, phi;
      asm("v_cvt_pk_bf16_f32 %0, %1, %2" : "=v"(plo) : "v"(h0[0]), "v"(h0[1]));
      asm("v_cvt_pk_bf16_f32 %0, %1, %2" : "=v"(phi) : "v"(h1[0]), "v"(h1[1]));
      uint2v pv = {plo, phi};
      *(uint2v*)(hs + col*128 + ((s*32 + q*8 + rot) & 127)) = pv;
    }
  }
#undef MM
#undef CELL

  // ---- projection: per-wave over its own 16 seqs (wave-local scratch,
  // in-order DS => no barrier). sigmoid(h_last @ fW.T + fb), fW in bf16.
  for (int task = l; task < 16*PP; task += 64) {
    int sl = task & 15, p = task >> 4;
    int rot2 = (sl & 7) << 4;
    float dot = fb_lds[p];
    #pragma unroll
    for (int kc = 0; kc < 8; ++kc) {
      short8 v = *(const short8*)(hs + sl*128 + (((kc<<4) + rot2) & 127));
      #pragma unroll
      for (int jj = 0; jj < 8; ++jj)
        dot += bf2f((unsigned short)v[jj]) * bf2f(fw_lds[p*64 + kc*8 + jj]);
    }
    float val = sigf(dot);
    int seq = wv*16 + sl;
    if (mode==0) {
      out_epi[(size_t)((b*PP + p)*NN + i)*130 + 2 + (s0+seq)] = val;   // raw cij
    } else if (mode==1) {
      out_epi[(size_t)((b*PP + p)*NN + (s0+seq))*130 + 0] = val;       // epi beta
    } else {
      out_epi[(size_t)((b*PP + p)*NN + (s0+seq))*130 + 1] = val;       // epi gamma
    }
  }
}

// softmax over j, in-place in epi rows (raw cij are sigmoids in (0,1) ->
// no max-subtract needed; softmax is shift-invariant).
__global__ __launch_bounds__(256) void softmax_epi(float* __restrict__ out_epi)
{
  int row = blockIdx.x*4 + (threadIdx.x >> 6);   // row = (b*14+p)*128 + i
  int l = threadIdx.x & 63;
  float* epi = out_epi + (size_t)row*130;
  float v0 = epi[2+l], v1 = epi[2+64+l];
  float e0 = fexp2(v0*1.44269504f), e1 = fexp2(v1*1.44269504f);
  float s = e0 + e1;
  #pragma unroll
  for (int off = 32; off; off >>= 1) s += __shfl_xor(s, off);
  float inv = frcp(s);
  epi[2+l] = e0*inv; epi[2+64+l] = e1*inv;
}

// sequential SIR scan over P steps; one WG per batch, 8 lanes per node,
// float2 loads with p+1 register prefetch. beta/gamma read from epi[...,0:2].
__global__ __launch_bounds__(1024) void sir_scan(
    const float* __restrict__ x,
    const float* __restrict__ epi,
    float* __restrict__ out0, float* __restrict__ out2, float* __restrict__ out3)
{
  __shared__ float Ish[NN];
  int b = blockIdx.x;
  int tid = threadIdx.x;
  int i = tid >> 3, q = tid & 7;
  const float* x0 = x + ((b*TT + 11)*NN + i)*3;
  float S = x0[0], I = x0[1], R = x0[2];
  if (q == 0) Ish[i] = I;

  float2v v[8], vn[8];
  {
    const float* crow = epi + (size_t)((b*PP + 0)*NN + i)*130 + 2 + q*16;
    #pragma unroll
    for (int jj = 0; jj < 8; ++jj) v[jj] = *(const float2v*)(crow + jj*2);
  }
  __syncthreads();
  for (int p = 0; p < PP; ++p) {
    if (p+1 < PP) {
      const float* crow = epi + (size_t)((b*PP + p+1)*NN + i)*130 + 2 + q*16;
      #pragma unroll
      for (int jj = 0; jj < 8; ++jj) vn[jj] = *(const float2v*)(crow + jj*2);
    }
    float part = 0.f;
    #pragma unroll
    for (int jj = 0; jj < 8; ++jj)
      part += v[jj][0]*Ish[q*16 + jj*2] + v[jj][1]*Ish[q*16 + jj*2 + 1];
    part += __shfl_xor(part, 1);
    part += __shfl_xor(part, 2);
    part += __shfl_xor(part, 4);
    __syncthreads();   // all Ish reads done
    if (q == 0) {
      const float* erow = epi + (size_t)((b*PP + p)*NN + i)*130;
      float beta  = erow[0];
      float gamma = erow[1];
      float Ntot = fmaxf(S+I+R, 1e-8f);
      float dS = -beta*S/Ntot*part;
      float dI = -dS - gamma*I;
      float dR = gamma*I;
      float St = fmaxf(S+dS, 0.f), It = fmaxf(I+dI, 0.f), Rt = fmaxf(R+dR, 0.f);
      float scale = Ntot / fmaxf(St+It+Rt, 1e-8f);
      float Inew = fmaxf(-dS, 0.f);
      int o = (b*PP+p)*NN + i;
      float Sn = St*scale, In = It*scale, Rn = Rt*scale;
      out0[o] = In;
      out2[o*3+0] = Sn; out2[o*3+1] = In; out2[o*3+2] = Rn;
      out3[o] = Inew;
      S = Sn; I = In; R = Rn;
      Ish[i] = I;
    }
    #pragma unroll
    for (int jj = 0; jj < 8; ++jj) v[jj] = vn[jj];
    __syncthreads();
  }
}

extern "C" void kernel_launch(void* const* d_in, const int* in_sizes, int n_in,
                              void* d_out, int out_size, void* d_ws, size_t ws_size,
                              hipStream_t stream) {
  const float* x_s  = (const float*)d_in[0];
  const float* x    = (const float*)d_in[1];
  const float* bWih = (const float*)d_in[2];
  const float* bWhh = (const float*)d_in[3];
  const float* bb_  = (const float*)d_in[4];
  const float* bfW  = (const float*)d_in[5];
  const float* bfb  = (const float*)d_in[6];
  const float* gWih = (const float*)d_in[7];
  const float* gWhh = (const float*)d_in[8];
  const float* gb_  = (const float*)d_in[9];
  const float* gfW  = (const float*)d_in[10];
  const float* gfb  = (const float*)d_in[11];
  const float* cWih = (const float*)d_in[12];
  const float* cWhh = (const float*)d_in[13];
  const float* cb_  = (const float*)d_in[14];
  const float* cfW  = (const float*)d_in[15];
  const float* cfb  = (const float*)d_in[16];

  float* out  = (float*)d_out;
  float* out0 = out;                              // (B,P,N,1)
  float* epi  = out + 7168;                       // (B,P,N,130)
  float* out2 = out + 7168 + 931840;              // (B,P,N,3)
  float* out3 = out + 7168 + 931840 + 21504;      // (B,P,N,1)

  hipLaunchKernelGGL(lstm_all, dim3(1040), dim3(256), 0, stream,
      x_s, bWih,bWhh,bb_,bfW,bfb, gWih,gWhh,gb_,gfW,gfb, cWih,cWhh,cb_,cfW,cfb,
      epi);
  hipLaunchKernelGGL(softmax_epi, dim3(1792), dim3(256), 0, stream, epi);
  hipLaunchKernelGGL(sir_scan, dim3(4), dim3(1024), 0, stream,
      x, epi, out0, out2, out3);
}

// Round 15
// 105.902 us; speedup vs baseline: 1.1449x; 1.1449x over previous
//
#include <hip/hip_runtime.h>

#define TT 12
#define NN 128
#define BB 4
#define PP 14

typedef __attribute__((ext_vector_type(8))) short short8;
typedef __attribute__((ext_vector_type(4))) float f32x4;
typedef __attribute__((ext_vector_type(2))) float float2v;
typedef __attribute__((ext_vector_type(2))) unsigned uint2v;

__device__ inline unsigned short f2bf(float x){
  unsigned u = __builtin_bit_cast(unsigned, x);
  u += 0x7fffu + ((u >> 16) & 1u);
  return (unsigned short)(u >> 16);
}
__device__ inline float bf2f(unsigned short h){
  unsigned u = ((unsigned)h) << 16;
  return __builtin_bit_cast(float, u);
}
__device__ inline float fexp2(float x){ return __builtin_amdgcn_exp2f(x); }
__device__ inline float frcp(float x){ return __builtin_amdgcn_rcpf(x); }
__device__ inline float sigf(float x){ return frcp(1.0f + fexp2(x * -1.44269504f)); }

__device__ inline float2v exp2v(float2v x){
  float2v r; r[0]=__builtin_amdgcn_exp2f(x[0]); r[1]=__builtin_amdgcn_exp2f(x[1]); return r;
}
// merged reciprocal: one trans op for both lanes (operands >=1, bounded)
__device__ inline float2v rcpv1(float2v x){
  float r = frcp(x[0]*x[1]);
  float2v o; o[0] = x[1]*r; o[1] = x[0]*r; return o;
}

// r15: r12 structure byte-identical EXCEPT the MFMA is inline asm with arch-
// VGPR ("v") constraints on A, B, and C/D. Rationale: rocprof's VGPR_Count=60
// excludes AGPRs; measured residency (10.5 waves/CU) implies ~130 hidden
// AGPRs — the compiler parks weight fragments + accumulators in the AGPR
// file, and the UNIFIED budget caps occupancy at 2.6 waves/SIMD. Forcing
// arch VGPRs empties the AGPR block -> unified ~135/wave -> ~15 waves/CU.
__global__ __launch_bounds__(256) void lstm_all(
    const float* __restrict__ x_s,
    const float* __restrict__ bWih, const float* __restrict__ bWhh, const float* __restrict__ bb_,
    const float* __restrict__ bfW,  const float* __restrict__ bfb,
    const float* __restrict__ gWih, const float* __restrict__ gWhh, const float* __restrict__ gb_,
    const float* __restrict__ gfW,  const float* __restrict__ gfb,
    const float* __restrict__ cWih, const float* __restrict__ cWhh, const float* __restrict__ cb_,
    const float* __restrict__ cfW,  const float* __restrict__ cfb,
    float* __restrict__ out_epi)
{
  __shared__ __align__(16) char hbuf[2*4096];             // [dbuf][32 seq][64 hu] bf16, rotate-swizzled
  __shared__ __align__(16) unsigned short xext[TT*32*8];  // [t][seq 0..31][8] bf16
  __shared__ float fw_lds[PP*64];
  __shared__ float fb_lds[PP];

  const int tid = threadIdx.x;
  const int l = tid & 63, w = tid >> 6;      // wave w owns hidden units [w*16, w*16+16)
  const int col = l & 15, q = l >> 4;

  const int rot = (col & 7) << 4;
  const int r0offA = col*128 + ((  0 + (q<<4) + rot) & 127);
  const int r1offA = col*128 + (( 64 + (q<<4) + rot) & 127);
  const int wroffA = col*128 + ((w*32 + q*8 + rot) & 127);
  const int r0offB = r0offA + 2048;
  const int r1offB = r1offA + 2048;
  const int wroffB = wroffA + 2048;

  int g0 = blockIdx.x << 1;
  int mode; const float *Wih, *Whh, *bias, *fW, *fb;
  if (g0 < 4096)      { mode=0; Wih=cWih; Whh=cWhh; bias=cb_; fW=cfW; fb=cfb; }
  else if (g0 < 4128) { mode=1; g0-=4096; Wih=bWih; Whh=bWhh; bias=bb_; fW=bfW; fb=bfb; }
  else                { mode=2; g0-=4128; Wih=gWih; Whh=gWhh; bias=gb_; fW=gfW; fb=gfb; }

  int b, i=0, s0;   // block covers seqs s0..s0+31 (j's for edge, n's for bg)
  if (mode==0) { b = g0 >> 10; int rem = g0 & 1023; i = rem >> 3; s0 = (rem & 7) << 4; }
  else         { b = g0 >> 3; s0 = (g0 & 7) << 4; }

  // ---- stage per-seq input extension [x | 1 | 0-pad] (bf16) for all timesteps
  for (int task = tid; task < TT*32; task += 256) {
    int t = task >> 5, m = task & 31;
    unsigned short* dst = &xext[(t*32+m)*8];
    float v0=0,v1=0,v2=0,v3=0,v4=0,v5=0,v6=0,v7=0;
    if (mode==0) {
      const float* xi = x_s + ((b*TT + t)*NN + i)*3;
      const float* xj = x_s + ((b*TT + t)*NN + (s0+m))*3;
      v0=xi[0]; v1=xi[1]; v2=xi[2]; v3=xj[0]; v4=xj[1]; v5=xj[2]; v6=1.f;
    } else {
      const float* xn = x_s + ((b*TT + t)*NN + (s0+m))*3;
      v0=xn[0]; v1=xn[1]; v2=xn[2]; v3=1.f;
    }
    dst[0]=f2bf(v0); dst[1]=f2bf(v1); dst[2]=f2bf(v2); dst[3]=f2bf(v3);
    dst[4]=f2bf(v4); dst[5]=f2bf(v5); dst[6]=f2bf(v6); dst[7]=f2bf(v7);
  }
  for (int idx = tid; idx < 1024; idx += 256) ((unsigned*)hbuf)[idx] = 0;  // zero buf0
  for (int idx = tid; idx < PP*64; idx += 256) fw_lds[idx] = fW[idx];
  if (tid < PP) fb_lds[tid] = fb[tid];

  // ---- pre-scaled weights as A-fragments: A[row=gate (l&15)][k = q*8+jj]
  short8 Aw[4][2]; short8 Ax[4];
  #pragma unroll
  for (int gt = 0; gt < 4; ++gt) {
    float sc = (gt==2) ? 2.88539008f : -1.44269504f;
    int gate = gt*64 + w*16 + col;
    #pragma unroll
    for (int kt = 0; kt < 2; ++kt) {
      const float* src = Whh + gate*64 + kt*32 + q*8;
      short8 fr;
      #pragma unroll
      for (int jj = 0; jj < 8; ++jj) fr[jj] = (short)f2bf(src[jj]*sc);
      Aw[gt][kt] = fr;
    }
    short8 ax = {0,0,0,0,0,0,0,0};
    if (q == 0) {
      if (mode==0) {
        ax[0]=(short)f2bf(Wih[gate*6+0]*sc); ax[1]=(short)f2bf(Wih[gate*6+1]*sc); ax[2]=(short)f2bf(Wih[gate*6+2]*sc);
        ax[3]=(short)f2bf(Wih[gate*6+3]*sc); ax[4]=(short)f2bf(Wih[gate*6+4]*sc); ax[5]=(short)f2bf(Wih[gate*6+5]*sc);
        ax[6]=(short)f2bf(bias[gate]*sc);
      } else {
        ax[0]=(short)f2bf(Wih[gate*3+0]*sc); ax[1]=(short)f2bf(Wih[gate*3+1]*sc); ax[2]=(short)f2bf(Wih[gate*3+2]*sc);
        ax[3]=(short)f2bf(bias[gate]*sc);
      }
    }
    Ax[gt] = ax;
  }

  __syncthreads();

  float2v cA0 = {0.f,0.f}, cA1 = {0.f,0.f}, cB0 = {0.f,0.f}, cB1 = {0.f,0.f};

// inline-asm MFMA: forces D/C, A, B into ARCH VGPRs (no AGPR allocation).
// ISA operand order: D, A, B, C  (acc is "+v" => D and C tied).
#define MM(acc, aop, bop) \
    asm("v_mfma_f32_16x16x32_bf16 %0, %1, %2, %0" : "+v"(acc) : "v"(aop), "v"(bop))
#define CELL(cvar, hvar, fF, fI, fG, fO) { \
    float2v Ei = exp2v(fI), Ef = exp2v(fF), Eg = exp2v(fG), Eo = exp2v(fO); \
    float2v t1 = (Ei + 1.0f) * (Eg + 1.0f); \
    float2v pf = Ef + 1.0f; \
    float2v num = cvar * t1 + pf * (Eg - 1.0f); \
    cvar = num * rcpv1(pf * t1); \
    float2v Ec = exp2v(cvar * 2.88539008f); \
    hvar = (Ec - 1.0f) * rcpv1((Ec + 1.0f) * (Eo + 1.0f)); }

// one 16-seq group: LDS loads -> 12 MFMAs -> CELL -> packed h write
#define GROUP(r0off, r1off, wroff, xoff, c0v, c1v) { \
    short8 b0 = *(const short8*)(rb + r0off); \
    short8 b1 = *(const short8*)(rb + r1off); \
    short8 bx = *(const short8*)&xext[(xoff)*8]; \
    f32x4 Fv = {0.f,0.f,0.f,0.f}, Iv = Fv, Gv = Fv, Ov = Fv; \
    MM(Fv, Aw[1][0], b0); MM(Iv, Aw[0][0], b0); MM(Gv, Aw[2][0], b0); MM(Ov, Aw[3][0], b0); \
    MM(Fv, Aw[1][1], b1); MM(Iv, Aw[0][1], b1); MM(Gv, Aw[2][1], b1); MM(Ov, Aw[3][1], b1); \
    MM(Fv, Ax[1], bx);    MM(Iv, Ax[0], bx);    MM(Gv, Ax[2], bx);    MM(Ov, Ax[3], bx); \
    float2v f0 = {Fv[0],Fv[1]}, f1 = {Fv[2],Fv[3]}; \
    float2v i0 = {Iv[0],Iv[1]}, i1 = {Iv[2],Iv[3]}; \
    float2v g0v = {Gv[0],Gv[1]}, g1v = {Gv[2],Gv[3]}; \
    float2v o0 = {Ov[0],Ov[1]}, o1 = {Ov[2],Ov[3]}; \
    float2v h0, h1; \
    CELL(c0v, h0, f0, i0, g0v, o0); \
    CELL(c1v, h1, f1, i1, g1v, o1); \
    unsigned plo, phi; \
    asm("v_cvt_pk_bf16_f32 %0, %1, %2" : "=v"(plo) : "v"(h0[0]), "v"(h0[1])); \
    asm("v_cvt_pk_bf16_f32 %0, %1, %2" : "=v"(phi) : "v"(h1[0]), "v"(h1[1])); \
    uint2v pv = {plo, phi}; \
    *(uint2v*)(wbp + wroff) = pv; }

  for (int t = 0; t < TT; ++t) {
    const char* rb = hbuf + ((t & 1) ? 4096 : 0);
    char* wbp      = hbuf + ((t & 1) ? 0 : 4096);
    // phase A: seqs s0..s0+15
    GROUP(r0offA, r1offA, wroffA, t*32 + col, cA0, cA1);
    __builtin_amdgcn_sched_barrier(0);   // keep B's loads/MFMAs out of A's live range
    // phase B: seqs s0+16..s0+31
    GROUP(r0offB, r1offB, wroffB, t*32 + 16 + col, cB0, cB1);
    __syncthreads();
  }
#undef MM
#undef CELL
#undef GROUP

  // ---- projection: sigmoid(h_last @ fW.T + fb); h(12) is in buf0 (TT even)
  const char* hfin = hbuf;
  for (int task = tid; task < 32*PP; task += 256) {
    int seq = task & 31, p = task >> 5;
    int rot2 = (seq & 7) << 4;
    float dot = fb_lds[p];
    #pragma unroll
    for (int kc = 0; kc < 8; ++kc) {
      short8 v = *(const short8*)(hfin + seq*128 + (((kc<<4) + rot2) & 127));
      #pragma unroll
      for (int jj = 0; jj < 8; ++jj)
        dot += bf2f((unsigned short)v[jj]) * fw_lds[p*64 + kc*8 + jj];
    }
    float val = sigf(dot);
    if (mode==0) {
      out_epi[(size_t)((b*PP + p)*NN + i)*130 + 2 + (s0+seq)] = val;   // raw cij
    } else if (mode==1) {
      out_epi[(size_t)((b*PP + p)*NN + (s0+seq))*130 + 0] = val;       // epi beta
    } else {
      out_epi[(size_t)((b*PP + p)*NN + (s0+seq))*130 + 1] = val;       // epi gamma
    }
  }
}

// softmax over j, in-place in epi rows (raw cij are sigmoids in (0,1) ->
// no max-subtract needed; softmax is shift-invariant).
__global__ __launch_bounds__(256) void softmax_epi(float* __restrict__ out_epi)
{
  int row = blockIdx.x*4 + (threadIdx.x >> 6);   // row = (b*14+p)*128 + i
  int l = threadIdx.x & 63;
  float* epi = out_epi + (size_t)row*130;
  float v0 = epi[2+l], v1 = epi[2+64+l];
  float e0 = fexp2(v0*1.44269504f), e1 = fexp2(v1*1.44269504f);
  float s = e0 + e1;
  #pragma unroll
  for (int off = 32; off; off >>= 1) s += __shfl_xor(s, off);
  float inv = frcp(s);
  epi[2+l] = e0*inv; epi[2+64+l] = e1*inv;
}

// sequential SIR scan over P steps; one WG per batch, 8 lanes per node,
// float2 loads with p+1 register prefetch. beta/gamma read from epi[...,0:2].
__global__ __launch_bounds__(1024) void sir_scan(
    const float* __restrict__ x,
    const float* __restrict__ epi,
    float* __restrict__ out0, float* __restrict__ out2, float* __restrict__ out3)
{
  __shared__ float Ish[NN];
  int b = blockIdx.x;
  int tid = threadIdx.x;
  int i = tid >> 3, q = tid & 7;
  const float* x0 = x + ((b*TT + 11)*NN + i)*3;
  float S = x0[0], I = x0[1], R = x0[2];
  if (q == 0) Ish[i] = I;

  float2v v[8], vn[8];
  {
    const float* crow = epi + (size_t)((b*PP + 0)*NN + i)*130 + 2 + q*16;
    #pragma unroll
    for (int jj = 0; jj < 8; ++jj) v[jj] = *(const float2v*)(crow + jj*2);
  }
  __syncthreads();
  for (int p = 0; p < PP; ++p) {
    if (p+1 < PP) {
      const float* crow = epi + (size_t)((b*PP + p+1)*NN + i)*130 + 2 + q*16;
      #pragma unroll
      for (int jj = 0; jj < 8; ++jj) vn[jj] = *(const float2v*)(crow + jj*2);
    }
    float part = 0.f;
    #pragma unroll
    for (int jj = 0; jj < 8; ++jj)
      part += v[jj][0]*Ish[q*16 + jj*2] + v[jj][1]*Ish[q*16 + jj*2 + 1];
    part += __shfl_xor(part, 1);
    part += __shfl_xor(part, 2);
    part += __shfl_xor(part, 4);
    __syncthreads();   // all Ish reads done
    if (q == 0) {
      const float* erow = epi + (size_t)((b*PP + p)*NN + i)*130;
      float beta  = erow[0];
      float gamma = erow[1];
      float Ntot = fmaxf(S+I+R, 1e-8f);
      float dS = -beta*S/Ntot*part;
      float dI = -dS - gamma*I;
      float dR = gamma*I;
      float St = fmaxf(S+dS, 0.f), It = fmaxf(I+dI, 0.f), Rt = fmaxf(R+dR, 0.f);
      float scale = Ntot / fmaxf(St+It+Rt, 1e-8f);
      float Inew = fmaxf(-dS, 0.f);
      int o = (b*PP+p)*NN + i;
      float Sn = St*scale, In = It*scale, Rn = Rt*scale;
      out0[o] = In;
      out2[o*3+0] = Sn; out2[o*3+1] = In; out2[o*3+2] = Rn;
      out3[o] = Inew;
      S = Sn; I = In; R = Rn;
      Ish[i] = I;
    }
    #pragma unroll
    for (int jj = 0; jj < 8; ++jj) v[jj] = vn[jj];
    __syncthreads();
  }
}

extern "C" void kernel_launch(void* const* d_in, const int* in_sizes, int n_in,
                              void* d_out, int out_size, void* d_ws, size_t ws_size,
                              hipStream_t stream) {
  const float* x_s  = (const float*)d_in[0];
  const float* x    = (const float*)d_in[1];
  const float* bWih = (const float*)d_in[2];
  const float* bWhh = (const float*)d_in[3];
  const float* bb_  = (const float*)d_in[4];
  const float* bfW  = (const float*)d_in[5];
  const float* bfb  = (const float*)d_in[6];
  const float* gWih = (const float*)d_in[7];
  const float* gWhh = (const float*)d_in[8];
  const float* gb_  = (const float*)d_in[9];
  const float* gfW  = (const float*)d_in[10];
  const float* gfb  = (const float*)d_in[11];
  const float* cWih = (const float*)d_in[12];
  const float* cWhh = (const float*)d_in[13];
  const float* cb_  = (const float*)d_in[14];
  const float* cfW  = (const float*)d_in[15];
  const float* cfb  = (const float*)d_in[16];

  float* out  = (float*)d_out;
  float* out0 = out;                              // (B,P,N,1)
  float* epi  = out + 7168;                       // (B,P,N,130)
  float* out2 = out + 7168 + 931840;              // (B,P,N,3)
  float* out3 = out + 7168 + 931840 + 21504;      // (B,P,N,1)

  hipLaunchKernelGGL(lstm_all, dim3(2080), dim3(256), 0, stream,
      x_s, bWih,bWhh,bb_,bfW,bfb, gWih,gWhh,gb_,gfW,gfb, cWih,cWhh,cb_,cfW,cfb,
      epi);
  hipLaunchKernelGGL(softmax_epi, dim3(1792), dim3(256), 0, stream, epi);
  hipLaunchKernelGGL(sir_scan, dim3(4), dim3(1024), 0, stream,
      x, epi, out0, out2, out3);
}

// Round 16
// 104.657 us; speedup vs baseline: 1.1585x; 1.0119x over previous
//
#include <hip/hip_runtime.h>

#define TT 12
#define NN 128
#define BB 4
#define PP 14

typedef __attribute__((ext_vector_type(8))) short short8;
typedef __attribute__((ext_vector_type(4))) float f32x4;
typedef __attribute__((ext_vector_type(2))) float float2v;
typedef __attribute__((ext_vector_type(2))) unsigned uint2v;

__device__ inline unsigned short f2bf(float x){
  unsigned u = __builtin_bit_cast(unsigned, x);
  u += 0x7fffu + ((u >> 16) & 1u);
  return (unsigned short)(u >> 16);
}
__device__ inline float bf2f(unsigned short h){
  unsigned u = ((unsigned)h) << 16;
  return __builtin_bit_cast(float, u);
}
__device__ inline float fexp2(float x){ return __builtin_amdgcn_exp2f(x); }
__device__ inline float frcp(float x){ return __builtin_amdgcn_rcpf(x); }
__device__ inline float sigf(float x){ return frcp(1.0f + fexp2(x * -1.44269504f)); }

__device__ inline float2v exp2v(float2v x){
  float2v r; r[0]=__builtin_amdgcn_exp2f(x[0]); r[1]=__builtin_amdgcn_exp2f(x[1]); return r;
}
// merged reciprocal: one trans op for both lanes (operands >=1, bounded)
__device__ inline float2v rcpv1(float2v x){
  float r = frcp(x[0]*x[1]);
  float2v o; o[0] = x[1]*r; o[1] = x[0]*r; return o;
}

// r16: r15 byte-identical EXCEPT the sched_barrier(0) between group A and
// group B is REMOVED. With asm-v MFMA the register landscape changed
// (52 VGPR); letting the compiler interleave B's ds_reads/MFMAs into A's
// 6-deep trans chain attacks the latency floor that six structural
// variants (r10-r15) left invariant at 86.5-88.6us.
__global__ __launch_bounds__(256) void lstm_all(
    const float* __restrict__ x_s,
    const float* __restrict__ bWih, const float* __restrict__ bWhh, const float* __restrict__ bb_,
    const float* __restrict__ bfW,  const float* __restrict__ bfb,
    const float* __restrict__ gWih, const float* __restrict__ gWhh, const float* __restrict__ gb_,
    const float* __restrict__ gfW,  const float* __restrict__ gfb,
    const float* __restrict__ cWih, const float* __restrict__ cWhh, const float* __restrict__ cb_,
    const float* __restrict__ cfW,  const float* __restrict__ cfb,
    float* __restrict__ out_epi)
{
  __shared__ __align__(16) char hbuf[2*4096];             // [dbuf][32 seq][64 hu] bf16, rotate-swizzled
  __shared__ __align__(16) unsigned short xext[TT*32*8];  // [t][seq 0..31][8] bf16
  __shared__ float fw_lds[PP*64];
  __shared__ float fb_lds[PP];

  const int tid = threadIdx.x;
  const int l = tid & 63, w = tid >> 6;      // wave w owns hidden units [w*16, w*16+16)
  const int col = l & 15, q = l >> 4;

  const int rot = (col & 7) << 4;
  const int r0offA = col*128 + ((  0 + (q<<4) + rot) & 127);
  const int r1offA = col*128 + (( 64 + (q<<4) + rot) & 127);
  const int wroffA = col*128 + ((w*32 + q*8 + rot) & 127);
  const int r0offB = r0offA + 2048;
  const int r1offB = r1offA + 2048;
  const int wroffB = wroffA + 2048;

  int g0 = blockIdx.x << 1;
  int mode; const float *Wih, *Whh, *bias, *fW, *fb;
  if (g0 < 4096)      { mode=0; Wih=cWih; Whh=cWhh; bias=cb_; fW=cfW; fb=cfb; }
  else if (g0 < 4128) { mode=1; g0-=4096; Wih=bWih; Whh=bWhh; bias=bb_; fW=bfW; fb=bfb; }
  else                { mode=2; g0-=4128; Wih=gWih; Whh=gWhh; bias=gb_; fW=gfW; fb=gfb; }

  int b, i=0, s0;   // block covers seqs s0..s0+31 (j's for edge, n's for bg)
  if (mode==0) { b = g0 >> 10; int rem = g0 & 1023; i = rem >> 3; s0 = (rem & 7) << 4; }
  else         { b = g0 >> 3; s0 = (g0 & 7) << 4; }

  // ---- stage per-seq input extension [x | 1 | 0-pad] (bf16) for all timesteps
  for (int task = tid; task < TT*32; task += 256) {
    int t = task >> 5, m = task & 31;
    unsigned short* dst = &xext[(t*32+m)*8];
    float v0=0,v1=0,v2=0,v3=0,v4=0,v5=0,v6=0,v7=0;
    if (mode==0) {
      const float* xi = x_s + ((b*TT + t)*NN + i)*3;
      const float* xj = x_s + ((b*TT + t)*NN + (s0+m))*3;
      v0=xi[0]; v1=xi[1]; v2=xi[2]; v3=xj[0]; v4=xj[1]; v5=xj[2]; v6=1.f;
    } else {
      const float* xn = x_s + ((b*TT + t)*NN + (s0+m))*3;
      v0=xn[0]; v1=xn[1]; v2=xn[2]; v3=1.f;
    }
    dst[0]=f2bf(v0); dst[1]=f2bf(v1); dst[2]=f2bf(v2); dst[3]=f2bf(v3);
    dst[4]=f2bf(v4); dst[5]=f2bf(v5); dst[6]=f2bf(v6); dst[7]=f2bf(v7);
  }
  for (int idx = tid; idx < 1024; idx += 256) ((unsigned*)hbuf)[idx] = 0;  // zero buf0
  for (int idx = tid; idx < PP*64; idx += 256) fw_lds[idx] = fW[idx];
  if (tid < PP) fb_lds[tid] = fb[tid];

  // ---- pre-scaled weights as A-fragments: A[row=gate (l&15)][k = q*8+jj]
  short8 Aw[4][2]; short8 Ax[4];
  #pragma unroll
  for (int gt = 0; gt < 4; ++gt) {
    float sc = (gt==2) ? 2.88539008f : -1.44269504f;
    int gate = gt*64 + w*16 + col;
    #pragma unroll
    for (int kt = 0; kt < 2; ++kt) {
      const float* src = Whh + gate*64 + kt*32 + q*8;
      short8 fr;
      #pragma unroll
      for (int jj = 0; jj < 8; ++jj) fr[jj] = (short)f2bf(src[jj]*sc);
      Aw[gt][kt] = fr;
    }
    short8 ax = {0,0,0,0,0,0,0,0};
    if (q == 0) {
      if (mode==0) {
        ax[0]=(short)f2bf(Wih[gate*6+0]*sc); ax[1]=(short)f2bf(Wih[gate*6+1]*sc); ax[2]=(short)f2bf(Wih[gate*6+2]*sc);
        ax[3]=(short)f2bf(Wih[gate*6+3]*sc); ax[4]=(short)f2bf(Wih[gate*6+4]*sc); ax[5]=(short)f2bf(Wih[gate*6+5]*sc);
        ax[6]=(short)f2bf(bias[gate]*sc);
      } else {
        ax[0]=(short)f2bf(Wih[gate*3+0]*sc); ax[1]=(short)f2bf(Wih[gate*3+1]*sc); ax[2]=(short)f2bf(Wih[gate*3+2]*sc);
        ax[3]=(short)f2bf(bias[gate]*sc);
      }
    }
    Ax[gt] = ax;
  }

  __syncthreads();

  float2v cA0 = {0.f,0.f}, cA1 = {0.f,0.f}, cB0 = {0.f,0.f}, cB1 = {0.f,0.f};

// inline-asm MFMA: forces D/C, A, B into ARCH VGPRs (no AGPR allocation).
#define MM(acc, aop, bop) \
    asm("v_mfma_f32_16x16x32_bf16 %0, %1, %2, %0" : "+v"(acc) : "v"(aop), "v"(bop))
#define CELL(cvar, hvar, fF, fI, fG, fO) { \
    float2v Ei = exp2v(fI), Ef = exp2v(fF), Eg = exp2v(fG), Eo = exp2v(fO); \
    float2v t1 = (Ei + 1.0f) * (Eg + 1.0f); \
    float2v pf = Ef + 1.0f; \
    float2v num = cvar * t1 + pf * (Eg - 1.0f); \
    cvar = num * rcpv1(pf * t1); \
    float2v Ec = exp2v(cvar * 2.88539008f); \
    hvar = (Ec - 1.0f) * rcpv1((Ec + 1.0f) * (Eo + 1.0f)); }

// one 16-seq group: LDS loads -> 12 MFMAs -> CELL -> packed h write
#define GROUP(r0off, r1off, wroff, xoff, c0v, c1v) { \
    short8 b0 = *(const short8*)(rb + r0off); \
    short8 b1 = *(const short8*)(rb + r1off); \
    short8 bx = *(const short8*)&xext[(xoff)*8]; \
    f32x4 Fv = {0.f,0.f,0.f,0.f}, Iv = Fv, Gv = Fv, Ov = Fv; \
    MM(Fv, Aw[1][0], b0); MM(Iv, Aw[0][0], b0); MM(Gv, Aw[2][0], b0); MM(Ov, Aw[3][0], b0); \
    MM(Fv, Aw[1][1], b1); MM(Iv, Aw[0][1], b1); MM(Gv, Aw[2][1], b1); MM(Ov, Aw[3][1], b1); \
    MM(Fv, Ax[1], bx);    MM(Iv, Ax[0], bx);    MM(Gv, Ax[2], bx);    MM(Ov, Ax[3], bx); \
    float2v f0 = {Fv[0],Fv[1]}, f1 = {Fv[2],Fv[3]}; \
    float2v i0 = {Iv[0],Iv[1]}, i1 = {Iv[2],Iv[3]}; \
    float2v g0v = {Gv[0],Gv[1]}, g1v = {Gv[2],Gv[3]}; \
    float2v o0 = {Ov[0],Ov[1]}, o1 = {Ov[2],Ov[3]}; \
    float2v h0, h1; \
    CELL(c0v, h0, f0, i0, g0v, o0); \
    CELL(c1v, h1, f1, i1, g1v, o1); \
    unsigned plo, phi; \
    asm("v_cvt_pk_bf16_f32 %0, %1, %2" : "=v"(plo) : "v"(h0[0]), "v"(h0[1])); \
    asm("v_cvt_pk_bf16_f32 %0, %1, %2" : "=v"(phi) : "v"(h1[0]), "v"(h1[1])); \
    uint2v pv = {plo, phi}; \
    *(uint2v*)(wbp + wroff) = pv; }

  for (int t = 0; t < TT; ++t) {
    const char* rb = hbuf + ((t & 1) ? 4096 : 0);
    char* wbp      = hbuf + ((t & 1) ? 0 : 4096);
    // groups A and B: no sched_barrier — compiler interleaves B's loads and
    // MFMAs into A's transcendental-chain stalls (r16 single change)
    GROUP(r0offA, r1offA, wroffA, t*32 + col, cA0, cA1);
    GROUP(r0offB, r1offB, wroffB, t*32 + 16 + col, cB0, cB1);
    __syncthreads();
  }
#undef MM
#undef CELL
#undef GROUP

  // ---- projection: sigmoid(h_last @ fW.T + fb); h(12) is in buf0 (TT even)
  const char* hfin = hbuf;
  for (int task = tid; task < 32*PP; task += 256) {
    int seq = task & 31, p = task >> 5;
    int rot2 = (seq & 7) << 4;
    float dot = fb_lds[p];
    #pragma unroll
    for (int kc = 0; kc < 8; ++kc) {
      short8 v = *(const short8*)(hfin + seq*128 + (((kc<<4) + rot2) & 127));
      #pragma unroll
      for (int jj = 0; jj < 8; ++jj)
        dot += bf2f((unsigned short)v[jj]) * fw_lds[p*64 + kc*8 + jj];
    }
    float val = sigf(dot);
    if (mode==0) {
      out_epi[(size_t)((b*PP + p)*NN + i)*130 + 2 + (s0+seq)] = val;   // raw cij
    } else if (mode==1) {
      out_epi[(size_t)((b*PP + p)*NN + (s0+seq))*130 + 0] = val;       // epi beta
    } else {
      out_epi[(size_t)((b*PP + p)*NN + (s0+seq))*130 + 1] = val;       // epi gamma
    }
  }
}

// softmax over j, in-place in epi rows (raw cij are sigmoids in (0,1) ->
// no max-subtract needed; softmax is shift-invariant).
__global__ __launch_bounds__(256) void softmax_epi(float* __restrict__ out_epi)
{
  int row = blockIdx.x*4 + (threadIdx.x >> 6);   // row = (b*14+p)*128 + i
  int l = threadIdx.x & 63;
  float* epi = out_epi + (size_t)row*130;
  float v0 = epi[2+l], v1 = epi[2+64+l];
  float e0 = fexp2(v0*1.44269504f), e1 = fexp2(v1*1.44269504f);
  float s = e0 + e1;
  #pragma unroll
  for (int off = 32; off; off >>= 1) s += __shfl_xor(s, off);
  float inv = frcp(s);
  epi[2+l] = e0*inv; epi[2+64+l] = e1*inv;
}

// sequential SIR scan over P steps; one WG per batch, 8 lanes per node,
// float2 loads with p+1 register prefetch. beta/gamma read from epi[...,0:2].
__global__ __launch_bounds__(1024) void sir_scan(
    const float* __restrict__ x,
    const float* __restrict__ epi,
    float* __restrict__ out0, float* __restrict__ out2, float* __restrict__ out3)
{
  __shared__ float Ish[NN];
  int b = blockIdx.x;
  int tid = threadIdx.x;
  int i = tid >> 3, q = tid & 7;
  const float* x0 = x + ((b*TT + 11)*NN + i)*3;
  float S = x0[0], I = x0[1], R = x0[2];
  if (q == 0) Ish[i] = I;

  float2v v[8], vn[8];
  {
    const float* crow = epi + (size_t)((b*PP + 0)*NN + i)*130 + 2 + q*16;
    #pragma unroll
    for (int jj = 0; jj < 8; ++jj) v[jj] = *(const float2v*)(crow + jj*2);
  }
  __syncthreads();
  for (int p = 0; p < PP; ++p) {
    if (p+1 < PP) {
      const float* crow = epi + (size_t)((b*PP + p+1)*NN + i)*130 + 2 + q*16;
      #pragma unroll
      for (int jj = 0; jj < 8; ++jj) vn[jj] = *(const float2v*)(crow + jj*2);
    }
    float part = 0.f;
    #pragma unroll
    for (int jj = 0; jj < 8; ++jj)
      part += v[jj][0]*Ish[q*16 + jj*2] + v[jj][1]*Ish[q*16 + jj*2 + 1];
    part += __shfl_xor(part, 1);
    part += __shfl_xor(part, 2);
    part += __shfl_xor(part, 4);
    __syncthreads();   // all Ish reads done
    if (q == 0) {
      const float* erow = epi + (size_t)((b*PP + p)*NN + i)*130;
      float beta  = erow[0];
      float gamma = erow[1];
      float Ntot = fmaxf(S+I+R, 1e-8f);
      float dS = -beta*S/Ntot*part;
      float dI = -dS - gamma*I;
      float dR = gamma*I;
      float St = fmaxf(S+dS, 0.f), It = fmaxf(I+dI, 0.f), Rt = fmaxf(R+dR, 0.f);
      float scale = Ntot / fmaxf(St+It+Rt, 1e-8f);
      float Inew = fmaxf(-dS, 0.f);
      int o = (b*PP+p)*NN + i;
      float Sn = St*scale, In = It*scale, Rn = Rt*scale;
      out0[o] = In;
      out2[o*3+0] = Sn; out2[o*3+1] = In; out2[o*3+2] = Rn;
      out3[o] = Inew;
      S = Sn; I = In; R = Rn;
      Ish[i] = I;
    }
    #pragma unroll
    for (int jj = 0; jj < 8; ++jj) v[jj] = vn[jj];
    __syncthreads();
  }
}

extern "C" void kernel_launch(void* const* d_in, const int* in_sizes, int n_in,
                              void* d_out, int out_size, void* d_ws, size_t ws_size,
                              hipStream_t stream) {
  const float* x_s  = (const float*)d_in[0];
  const float* x    = (const float*)d_in[1];
  const float* bWih = (const float*)d_in[2];
  const float* bWhh = (const float*)d_in[3];
  const float* bb_  = (const float*)d_in[4];
  const float* bfW  = (const float*)d_in[5];
  const float* bfb  = (const float*)d_in[6];
  const float* gWih = (const float*)d_in[7];
  const float* gWhh = (const float*)d_in[8];
  const float* gb_  = (const float*)d_in[9];
  const float* gfW  = (const float*)d_in[10];
  const float* gfb  = (const float*)d_in[11];
  const float* cWih = (const float*)d_in[12];
  const float* cWhh = (const float*)d_in[13];
  const float* cb_  = (const float*)d_in[14];
  const float* cfW  = (const float*)d_in[15];
  const float* cfb  = (const float*)d_in[16];

  float* out  = (float*)d_out;
  float* out0 = out;                              // (B,P,N,1)
  float* epi  = out + 7168;                       // (B,P,N,130)
  float* out2 = out + 7168 + 931840;              // (B,P,N,3)
  float* out3 = out + 7168 + 931840 + 21504;      // (B,P,N,1)

  hipLaunchKernelGGL(lstm_all, dim3(2080), dim3(256), 0, stream,
      x_s, bWih,bWhh,bb_,bfW,bfb, gWih,gWhh,gb_,gfW,gfb, cWih,cWhh,cb_,cfW,cfb,
      epi);
  hipLaunchKernelGGL(softmax_epi, dim3(1792), dim3(256), 0, stream, epi);
  hipLaunchKernelGGL(sir_scan, dim3(4), dim3(1024), 0, stream,
      x, epi, out0, out2, out3);
}

// Round 17
// 104.463 us; speedup vs baseline: 1.1607x; 1.0019x over previous
//
#include <hip/hip_runtime.h>

#define TT 12
#define NN 128
#define BB 4
#define PP 14

typedef __attribute__((ext_vector_type(8))) short short8;
typedef __attribute__((ext_vector_type(4))) float f32x4;
typedef __attribute__((ext_vector_type(2))) float float2v;
typedef __attribute__((ext_vector_type(2))) unsigned uint2v;

__device__ inline unsigned short f2bf(float x){
  unsigned u = __builtin_bit_cast(unsigned, x);
  u += 0x7fffu + ((u >> 16) & 1u);
  return (unsigned short)(u >> 16);
}
__device__ inline float bf2f(unsigned short h){
  unsigned u = ((unsigned)h) << 16;
  return __builtin_bit_cast(float, u);
}
__device__ inline float fexp2(float x){ return __builtin_amdgcn_exp2f(x); }
__device__ inline float frcp(float x){ return __builtin_amdgcn_rcpf(x); }
__device__ inline float sigf(float x){ return frcp(1.0f + fexp2(x * -1.44269504f)); }

__device__ inline float2v exp2v(float2v x){
  float2v r; r[0]=__builtin_amdgcn_exp2f(x[0]); r[1]=__builtin_amdgcn_exp2f(x[1]); return r;
}
// merged reciprocal: one trans op for both lanes (operands >=1, bounded)
__device__ inline float2v rcpv1(float2v x){
  float r = frcp(x[0]*x[1]);
  float2v o; o[0] = x[1]*r; o[1] = x[0]*r; return o;
}

// r17: r16 byte-identical EXCEPT __launch_bounds__(256, 3).
// Rationale: measured residency is ~10.4 waves/CU in BOTH 256-thr (r16) and
// 512-thr (r13) shapes -> unified allocation ~196 regs/wave vs reported
// VGPR 52-60 and a live-value census of ~125. The ~70-reg gap is allocator
// slack (hidden AGPR block). waves_per_eu=3 sets a 170-reg budget: above
// census need (no spill expected) but below current allocation -> 3
// waves/SIMD. Spill canary: FETCH/WRITE_SIZE must stay ~1.2/4.4 MB (r9's
// forced-8 disaster showed 860/620 MB).
__global__ __launch_bounds__(256, 3) void lstm_all(
    const float* __restrict__ x_s,
    const float* __restrict__ bWih, const float* __restrict__ bWhh, const float* __restrict__ bb_,
    const float* __restrict__ bfW,  const float* __restrict__ bfb,
    const float* __restrict__ gWih, const float* __restrict__ gWhh, const float* __restrict__ gb_,
    const float* __restrict__ gfW,  const float* __restrict__ gfb,
    const float* __restrict__ cWih, const float* __restrict__ cWhh, const float* __restrict__ cb_,
    const float* __restrict__ cfW,  const float* __restrict__ cfb,
    float* __restrict__ out_epi)
{
  __shared__ __align__(16) char hbuf[2*4096];             // [dbuf][32 seq][64 hu] bf16, rotate-swizzled
  __shared__ __align__(16) unsigned short xext[TT*32*8];  // [t][seq 0..31][8] bf16
  __shared__ float fw_lds[PP*64];
  __shared__ float fb_lds[PP];

  const int tid = threadIdx.x;
  const int l = tid & 63, w = tid >> 6;      // wave w owns hidden units [w*16, w*16+16)
  const int col = l & 15, q = l >> 4;

  const int rot = (col & 7) << 4;
  const int r0offA = col*128 + ((  0 + (q<<4) + rot) & 127);
  const int r1offA = col*128 + (( 64 + (q<<4) + rot) & 127);
  const int wroffA = col*128 + ((w*32 + q*8 + rot) & 127);
  const int r0offB = r0offA + 2048;
  const int r1offB = r1offA + 2048;
  const int wroffB = wroffA + 2048;

  int g0 = blockIdx.x << 1;
  int mode; const float *Wih, *Whh, *bias, *fW, *fb;
  if (g0 < 4096)      { mode=0; Wih=cWih; Whh=cWhh; bias=cb_; fW=cfW; fb=cfb; }
  else if (g0 < 4128) { mode=1; g0-=4096; Wih=bWih; Whh=bWhh; bias=bb_; fW=bfW; fb=bfb; }
  else                { mode=2; g0-=4128; Wih=gWih; Whh=gWhh; bias=gb_; fW=gfW; fb=gfb; }

  int b, i=0, s0;   // block covers seqs s0..s0+31 (j's for edge, n's for bg)
  if (mode==0) { b = g0 >> 10; int rem = g0 & 1023; i = rem >> 3; s0 = (rem & 7) << 4; }
  else         { b = g0 >> 3; s0 = (g0 & 7) << 4; }

  // ---- stage per-seq input extension [x | 1 | 0-pad] (bf16) for all timesteps
  for (int task = tid; task < TT*32; task += 256) {
    int t = task >> 5, m = task & 31;
    unsigned short* dst = &xext[(t*32+m)*8];
    float v0=0,v1=0,v2=0,v3=0,v4=0,v5=0,v6=0,v7=0;
    if (mode==0) {
      const float* xi = x_s + ((b*TT + t)*NN + i)*3;
      const float* xj = x_s + ((b*TT + t)*NN + (s0+m))*3;
      v0=xi[0]; v1=xi[1]; v2=xi[2]; v3=xj[0]; v4=xj[1]; v5=xj[2]; v6=1.f;
    } else {
      const float* xn = x_s + ((b*TT + t)*NN + (s0+m))*3;
      v0=xn[0]; v1=xn[1]; v2=xn[2]; v3=1.f;
    }
    dst[0]=f2bf(v0); dst[1]=f2bf(v1); dst[2]=f2bf(v2); dst[3]=f2bf(v3);
    dst[4]=f2bf(v4); dst[5]=f2bf(v5); dst[6]=f2bf(v6); dst[7]=f2bf(v7);
  }
  for (int idx = tid; idx < 1024; idx += 256) ((unsigned*)hbuf)[idx] = 0;  // zero buf0
  for (int idx = tid; idx < PP*64; idx += 256) fw_lds[idx] = fW[idx];
  if (tid < PP) fb_lds[tid] = fb[tid];

  // ---- pre-scaled weights as A-fragments: A[row=gate (l&15)][k = q*8+jj]
  short8 Aw[4][2]; short8 Ax[4];
  #pragma unroll
  for (int gt = 0; gt < 4; ++gt) {
    float sc = (gt==2) ? 2.88539008f : -1.44269504f;
    int gate = gt*64 + w*16 + col;
    #pragma unroll
    for (int kt = 0; kt < 2; ++kt) {
      const float* src = Whh + gate*64 + kt*32 + q*8;
      short8 fr;
      #pragma unroll
      for (int jj = 0; jj < 8; ++jj) fr[jj] = (short)f2bf(src[jj]*sc);
      Aw[gt][kt] = fr;
    }
    short8 ax = {0,0,0,0,0,0,0,0};
    if (q == 0) {
      if (mode==0) {
        ax[0]=(short)f2bf(Wih[gate*6+0]*sc); ax[1]=(short)f2bf(Wih[gate*6+1]*sc); ax[2]=(short)f2bf(Wih[gate*6+2]*sc);
        ax[3]=(short)f2bf(Wih[gate*6+3]*sc); ax[4]=(short)f2bf(Wih[gate*6+4]*sc); ax[5]=(short)f2bf(Wih[gate*6+5]*sc);
        ax[6]=(short)f2bf(bias[gate]*sc);
      } else {
        ax[0]=(short)f2bf(Wih[gate*3+0]*sc); ax[1]=(short)f2bf(Wih[gate*3+1]*sc); ax[2]=(short)f2bf(Wih[gate*3+2]*sc);
        ax[3]=(short)f2bf(bias[gate]*sc);
      }
    }
    Ax[gt] = ax;
  }

  __syncthreads();

  float2v cA0 = {0.f,0.f}, cA1 = {0.f,0.f}, cB0 = {0.f,0.f}, cB1 = {0.f,0.f};

// inline-asm MFMA: forces D/C, A, B into ARCH VGPRs (no AGPR allocation).
#define MM(acc, aop, bop) \
    asm("v_mfma_f32_16x16x32_bf16 %0, %1, %2, %0" : "+v"(acc) : "v"(aop), "v"(bop))
#define CELL(cvar, hvar, fF, fI, fG, fO) { \
    float2v Ei = exp2v(fI), Ef = exp2v(fF), Eg = exp2v(fG), Eo = exp2v(fO); \
    float2v t1 = (Ei + 1.0f) * (Eg + 1.0f); \
    float2v pf = Ef + 1.0f; \
    float2v num = cvar * t1 + pf * (Eg - 1.0f); \
    cvar = num * rcpv1(pf * t1); \
    float2v Ec = exp2v(cvar * 2.88539008f); \
    hvar = (Ec - 1.0f) * rcpv1((Ec + 1.0f) * (Eo + 1.0f)); }

// one 16-seq group: LDS loads -> 12 MFMAs -> CELL -> packed h write
#define GROUP(r0off, r1off, wroff, xoff, c0v, c1v) { \
    short8 b0 = *(const short8*)(rb + r0off); \
    short8 b1 = *(const short8*)(rb + r1off); \
    short8 bx = *(const short8*)&xext[(xoff)*8]; \
    f32x4 Fv = {0.f,0.f,0.f,0.f}, Iv = Fv, Gv = Fv, Ov = Fv; \
    MM(Fv, Aw[1][0], b0); MM(Iv, Aw[0][0], b0); MM(Gv, Aw[2][0], b0); MM(Ov, Aw[3][0], b0); \
    MM(Fv, Aw[1][1], b1); MM(Iv, Aw[0][1], b1); MM(Gv, Aw[2][1], b1); MM(Ov, Aw[3][1], b1); \
    MM(Fv, Ax[1], bx);    MM(Iv, Ax[0], bx);    MM(Gv, Ax[2], bx);    MM(Ov, Ax[3], bx); \
    float2v f0 = {Fv[0],Fv[1]}, f1 = {Fv[2],Fv[3]}; \
    float2v i0 = {Iv[0],Iv[1]}, i1 = {Iv[2],Iv[3]}; \
    float2v g0v = {Gv[0],Gv[1]}, g1v = {Gv[2],Gv[3]}; \
    float2v o0 = {Ov[0],Ov[1]}, o1 = {Ov[2],Ov[3]}; \
    float2v h0, h1; \
    CELL(c0v, h0, f0, i0, g0v, o0); \
    CELL(c1v, h1, f1, i1, g1v, o1); \
    unsigned plo, phi; \
    asm("v_cvt_pk_bf16_f32 %0, %1, %2" : "=v"(plo) : "v"(h0[0]), "v"(h0[1])); \
    asm("v_cvt_pk_bf16_f32 %0, %1, %2" : "=v"(phi) : "v"(h1[0]), "v"(h1[1])); \
    uint2v pv = {plo, phi}; \
    *(uint2v*)(wbp + wroff) = pv; }

  for (int t = 0; t < TT; ++t) {
    const char* rb = hbuf + ((t & 1) ? 4096 : 0);
    char* wbp      = hbuf + ((t & 1) ? 0 : 4096);
    GROUP(r0offA, r1offA, wroffA, t*32 + col, cA0, cA1);
    GROUP(r0offB, r1offB, wroffB, t*32 + 16 + col, cB0, cB1);
    __syncthreads();
  }
#undef MM
#undef CELL
#undef GROUP

  // ---- projection: sigmoid(h_last @ fW.T + fb); h(12) is in buf0 (TT even)
  const char* hfin = hbuf;
  for (int task = tid; task < 32*PP; task += 256) {
    int seq = task & 31, p = task >> 5;
    int rot2 = (seq & 7) << 4;
    float dot = fb_lds[p];
    #pragma unroll
    for (int kc = 0; kc < 8; ++kc) {
      short8 v = *(const short8*)(hfin + seq*128 + (((kc<<4) + rot2) & 127));
      #pragma unroll
      for (int jj = 0; jj < 8; ++jj)
        dot += bf2f((unsigned short)v[jj]) * fw_lds[p*64 + kc*8 + jj];
    }
    float val = sigf(dot);
    if (mode==0) {
      out_epi[(size_t)((b*PP + p)*NN + i)*130 + 2 + (s0+seq)] = val;   // raw cij
    } else if (mode==1) {
      out_epi[(size_t)((b*PP + p)*NN + (s0+seq))*130 + 0] = val;       // epi beta
    } else {
      out_epi[(size_t)((b*PP + p)*NN + (s0+seq))*130 + 1] = val;       // epi gamma
    }
  }
}

// softmax over j, in-place in epi rows (raw cij are sigmoids in (0,1) ->
// no max-subtract needed; softmax is shift-invariant).
__global__ __launch_bounds__(256) void softmax_epi(float* __restrict__ out_epi)
{
  int row = blockIdx.x*4 + (threadIdx.x >> 6);   // row = (b*14+p)*128 + i
  int l = threadIdx.x & 63;
  float* epi = out_epi + (size_t)row*130;
  float v0 = epi[2+l], v1 = epi[2+64+l];
  float e0 = fexp2(v0*1.44269504f), e1 = fexp2(v1*1.44269504f);
  float s = e0 + e1;
  #pragma unroll
  for (int off = 32; off; off >>= 1) s += __shfl_xor(s, off);
  float inv = frcp(s);
  epi[2+l] = e0*inv; epi[2+64+l] = e1*inv;
}

// sequential SIR scan over P steps; one WG per batch, 8 lanes per node,
// float2 loads with p+1 register prefetch. beta/gamma read from epi[...,0:2].
__global__ __launch_bounds__(1024) void sir_scan(
    const float* __restrict__ x,
    const float* __restrict__ epi,
    float* __restrict__ out0, float* __restrict__ out2, float* __restrict__ out3)
{
  __shared__ float Ish[NN];
  int b = blockIdx.x;
  int tid = threadIdx.x;
  int i = tid >> 3, q = tid & 7;
  const float* x0 = x + ((b*TT + 11)*NN + i)*3;
  float S = x0[0], I = x0[1], R = x0[2];
  if (q == 0) Ish[i] = I;

  float2v v[8], vn[8];
  {
    const float* crow = epi + (size_t)((b*PP + 0)*NN + i)*130 + 2 + q*16;
    #pragma unroll
    for (int jj = 0; jj < 8; ++jj) v[jj] = *(const float2v*)(crow + jj*2);
  }
  __syncthreads();
  for (int p = 0; p < PP; ++p) {
    if (p+1 < PP) {
      const float* crow = epi + (size_t)((b*PP + p+1)*NN + i)*130 + 2 + q*16;
      #pragma unroll
      for (int jj = 0; jj < 8; ++jj) vn[jj] = *(const float2v*)(crow + jj*2);
    }
    float part = 0.f;
    #pragma unroll
    for (int jj = 0; jj < 8; ++jj)
      part += v[jj][0]*Ish[q*16 + jj*2] + v[jj][1]*Ish[q*16 + jj*2 + 1];
    part += __shfl_xor(part, 1);
    part += __shfl_xor(part, 2);
    part += __shfl_xor(part, 4);
    __syncthreads();   // all Ish reads done
    if (q == 0) {
      const float* erow = epi + (size_t)((b*PP + p)*NN + i)*130;
      float beta  = erow[0];
      float gamma = erow[1];
      float Ntot = fmaxf(S+I+R, 1e-8f);
      float dS = -beta*S/Ntot*part;
      float dI = -dS - gamma*I;
      float dR = gamma*I;
      float St = fmaxf(S+dS, 0.f), It = fmaxf(I+dI, 0.f), Rt = fmaxf(R+dR, 0.f);
      float scale = Ntot / fmaxf(St+It+Rt, 1e-8f);
      float Inew = fmaxf(-dS, 0.f);
      int o = (b*PP+p)*NN + i;
      float Sn = St*scale, In = It*scale, Rn = Rt*scale;
      out0[o] = In;
      out2[o*3+0] = Sn; out2[o*3+1] = In; out2[o*3+2] = Rn;
      out3[o] = Inew;
      S = Sn; I = In; R = Rn;
      Ish[i] = I;
    }
    #pragma unroll
    for (int jj = 0; jj < 8; ++jj) v[jj] = vn[jj];
    __syncthreads();
  }
}

extern "C" void kernel_launch(void* const* d_in, const int* in_sizes, int n_in,
                              void* d_out, int out_size, void* d_ws, size_t ws_size,
                              hipStream_t stream) {
  const float* x_s  = (const float*)d_in[0];
  const float* x    = (const float*)d_in[1];
  const float* bWih = (const float*)d_in[2];
  const float* bWhh = (const float*)d_in[3];
  const float* bb_  = (const float*)d_in[4];
  const float* bfW  = (const float*)d_in[5];
  const float* bfb  = (const float*)d_in[6];
  const float* gWih = (const float*)d_in[7];
  const float* gWhh = (const float*)d_in[8];
  const float* gb_  = (const float*)d_in[9];
  const float* gfW  = (const float*)d_in[10];
  const float* gfb  = (const float*)d_in[11];
  const float* cWih = (const float*)d_in[12];
  const float* cWhh = (const float*)d_in[13];
  const float* cb_  = (const float*)d_in[14];
  const float* cfW  = (const float*)d_in[15];
  const float* cfb  = (const float*)d_in[16];

  float* out  = (float*)d_out;
  float* out0 = out;                              // (B,P,N,1)
  float* epi  = out + 7168;                       // (B,P,N,130)
  float* out2 = out + 7168 + 931840;              // (B,P,N,3)
  float* out3 = out + 7168 + 931840 + 21504;      // (B,P,N,1)

  hipLaunchKernelGGL(lstm_all, dim3(2080), dim3(256), 0, stream,
      x_s, bWih,bWhh,bb_,bfW,bfb, gWih,gWhh,gb_,gfW,gfb, cWih,cWhh,cb_,cfW,cfb,
      epi);
  hipLaunchKernelGGL(softmax_epi, dim3(1792), dim3(256), 0, stream, epi);
  hipLaunchKernelGGL(sir_scan, dim3(4), dim3(1024), 0, stream,
      x, epi, out0, out2, out3);
}